// Round 2
// baseline (1323.234 us; speedup 1.0000x reference)
//
#include <hip/hip_runtime.h>

#define N_NODES 100000
#define N_EDGES 1600000
#define DIM     128
#define EPS_BN  1e-5f
#define NB      1024     // buckets
#define NPB     98       // nodes per bucket (1024*98 = 100352 >= 100000)
#define NBLK    256      // bin_scatter blocks
#define EPB     6250     // edges per bin_scatter block (256*6250 == N_EDGES)
#define CAP     2048     // slot capacity per bucket (mean 1562.5, sigma~40, +12σ)
#define M_TILE  64
#define M_PAD   100032   // 1563 * 64
#define GBLK    1563     // M_PAD / M_TILE
#define LPITCH  136      // LDS pitch in bf16 units (272B = 17*16B, b128-aligned)

typedef __attribute__((ext_vector_type(8))) short short8;
typedef __attribute__((ext_vector_type(4))) float floatx4;

__device__ __forceinline__ unsigned short f2bf(float f) {   // RNE bf16 bits
    unsigned u = __float_as_uint(f);
    return (unsigned short)((u + 0x7FFF + ((u >> 16) & 1)) >> 16);
}
__device__ __forceinline__ float bf2f(unsigned short b) {
    return __uint_as_float((unsigned)b << 16);
}

// int64 layout => odd int32 words all zero. Wave-uniform result.
__device__ __forceinline__ int detect64(const void* eidx) {
    int v = ((const int*)eidx)[2 * (threadIdx.x & 63) + 1];
    unsigned long long b = __ballot(v != 0);
    return (b == 0ULL) ? 1 : 0;
}
__device__ __forceinline__ int load_row(const void* eidx, int is64, int e) {
    if (is64) return (int)((const long long*)eidx)[e];
    return ((const int*)eidx)[e];
}
__device__ __forceinline__ int load_col(const void* eidx, int is64, int e) {
    if (is64) return (int)((const long long*)eidx)[N_EDGES + e];
    return ((const int*)eidx)[N_EDGES + e];
}

// ---------------------------------------------------------------------------
// xconv_w: x (f32) -> xb (bf16) row-major; blocks 0/1 also transpose W1/W2 to
// bf16 [n][k]; block 2 also zeroes bcur + gstats.
// ---------------------------------------------------------------------------
__global__ void xconv_w(const float* __restrict__ x,
                        unsigned short* __restrict__ xb,
                        const float* __restrict__ W1,
                        const float* __restrict__ W2,
                        unsigned short* __restrict__ W1t,
                        unsigned short* __restrict__ W2t,
                        int* __restrict__ bcur, float* __restrict__ gstats) {
    int i = blockIdx.x * 256 + threadIdx.x;
    float4 v = ((const float4*)x)[i];
    ushort4 o;
    o.x = f2bf(v.x); o.y = f2bf(v.y); o.z = f2bf(v.z); o.w = f2bf(v.w);
    ((ushort4*)xb)[i] = o;
    if (blockIdx.x < 2) {
        const float* W = blockIdx.x ? W2 : W1;
        unsigned short* Wt = blockIdx.x ? W2t : W1t;
        for (int j = threadIdx.x; j < DIM * DIM; j += 256) {
            int k = j >> 7, n = j & 127;
            Wt[n * DIM + k] = f2bf(W[j]);
        }
    } else if (blockIdx.x == 2) {
        int t = threadIdx.x;
        bcur[t] = 0; bcur[t + 256] = 0; bcur[t + 512] = 0; bcur[t + 768] = 0;
        if (t < 2 * DIM) gstats[t] = 0.f;
    }
}

// ---------------------------------------------------------------------------
// bin_scatter: hist -> LDS scan (1024 buckets, 4/thread) -> per-bucket global
// range claim -> LDS bucket-sorted staging (packed 4B: row_local<<24 | col)
// with precomputed absolute slot addresses -> LINEAR copy out.
// LDS: 3*4KB tables + 25KB stage + 25KB gaddr = 62.3KB.
// ---------------------------------------------------------------------------
__global__ __launch_bounds__(256) void bin_scatter(const void* eidx, int* bcur,
                                                   unsigned* __restrict__ slots) {
    __shared__ int lh[NB];
    __shared__ int lbase[NB];
    __shared__ int loff[NB];
    __shared__ unsigned stage[EPB];
    __shared__ int gaddr[EPB];
    int t = threadIdx.x;
    int is64 = detect64(eidx);
    lh[t] = 0; lh[t + 256] = 0; lh[t + 512] = 0; lh[t + 768] = 0;
    __syncthreads();
    int base = blockIdx.x * EPB;
    for (int i = t; i < EPB; i += 256) {
        int r = load_row(eidx, is64, base + i);
        atomicAdd(&lh[r / NPB], 1);
    }
    __syncthreads();
    // inclusive scan of lh[0..1023] into loff (256 threads, 4 elems each)
    loff[t] = lh[t]; loff[t + 256] = lh[t + 256];
    loff[t + 512] = lh[t + 512]; loff[t + 768] = lh[t + 768];
    __syncthreads();
    for (int off = 1; off < NB; off <<= 1) {
        int a0 = (t >= off) ? loff[t - off] : 0;
        int a1 = (t + 256 >= off) ? loff[t + 256 - off] : 0;
        int a2 = (t + 512 >= off) ? loff[t + 512 - off] : 0;
        int a3 = (t + 768 >= off) ? loff[t + 768 - off] : 0;
        __syncthreads();
        loff[t] += a0; loff[t + 256] += a1;
        loff[t + 512] += a2; loff[t + 768] += a3;
        __syncthreads();
    }
    // claim global ranges, make loff exclusive, reset lh for scatter cursors
#pragma unroll
    for (int q = 0; q < 4; ++q) {
        int i = t + 256 * q;
        int c = lh[i];
        lbase[i] = c ? atomicAdd(&bcur[i], c) : 0;
        loff[i] -= c;
        lh[i] = 0;
    }
    __syncthreads();
    for (int i = t; i < EPB; i += 256) {
        int r = load_row(eidx, is64, base + i);
        int c = load_col(eidx, is64, base + i);
        int b = r / NPB;
        int pos = atomicAdd(&lh[b], 1);
        int idx = loff[b] + pos;
        stage[idx] = ((unsigned)(r - b * NPB) << 24) | (unsigned)c;
        gaddr[idx] = b * CAP + lbase[b] + pos;
    }
    __syncthreads();
    for (int i = t; i < EPB; i += 256)        // linear: runs coalesce to lines
        slots[gaddr[i]] = stage[i];
}

// ---------------------------------------------------------------------------
// agg_bucket: replaces build_csr + agg_kernel. One block per bucket; per-node
// f32 accumulators live in LDS (98x128 = 50KB). Each wave takes a contiguous
// quarter of the bucket's edges, 16-deep pipelined gather (wave-uniform row
// base via readlane, lane-offset 4B loads -> 256B coalesced), then 2 LDS f32
// atomics per edge per lane (2-way bank alias = free). Self row + bf16 pack
// on the way out.
// ---------------------------------------------------------------------------
__global__ __launch_bounds__(256) void agg_bucket(
    const unsigned short* __restrict__ xb,
    const unsigned* __restrict__ slots,
    const int* __restrict__ bcnt,
    unsigned short* __restrict__ Hbf) {
    __shared__ float acc[NPB * DIM];          // 50176 B
    int t = threadIdx.x;
    int b = blockIdx.x;
    int lane = t & 63, wv = t >> 6;
    const unsigned* xbw = (const unsigned*)xb;    // 64 words per row
    for (int i = t; i < NPB * DIM; i += 256) acc[i] = 0.f;
    __syncthreads();
    int cnt = bcnt[b];
    const unsigned* pr = slots + (size_t)b * CAP;
    int es = (cnt * wv) >> 2;
    int ee = (cnt * (wv + 1)) >> 2;
    for (int j = es; j < ee; j += 64) {
        int li = j + lane;
        unsigned sl = pr[li < ee ? li : (ee - 1)];
        int nvalid = ee - j;                      // wave-uniform
#pragma unroll
        for (int g4 = 0; g4 < 4; ++g4) {
            if (g4 * 16 < nvalid) {               // uniform branch
                unsigned pw[16];
                int rl[16];
#pragma unroll
                for (int u = 0; u < 16; ++u) {
                    unsigned sv = __shfl(sl, g4 * 16 + u);
                    rl[u] = (int)(sv >> 24);
                    int col = (int)(sv & 0xFFFFFFu);
                    pw[u] = xbw[(size_t)col * 64 + lane];
                }
#pragma unroll
                for (int u = 0; u < 16; ++u) {
                    if (g4 * 16 + u < nvalid) {   // uniform branch
                        atomicAdd(&acc[rl[u] * DIM + lane * 2],
                                  __uint_as_float(pw[u] << 16));
                        atomicAdd(&acc[rl[u] * DIM + lane * 2 + 1],
                                  __uint_as_float(pw[u] & 0xffff0000u));
                    }
                }
            }
        }
    }
    __syncthreads();
    int node0 = b * NPB;
    int nn = N_NODES - node0;
    if (nn > NPB) nn = NPB;
    for (int r = wv; r < nn; r += 4) {
        unsigned selfw = xbw[(size_t)(node0 + r) * 64 + lane];
        float2 a = *(const float2*)(&acc[r * DIM + lane * 2]);
        float lo = a.x + __uint_as_float(selfw << 16);
        float hi = a.y + __uint_as_float(selfw & 0xffff0000u);
        unsigned pack = (unsigned)f2bf(lo) | ((unsigned)f2bf(hi) << 16);
        ((unsigned*)Hbf)[(size_t)(node0 + r) * 64 + lane] = pack;
    }
}

// ---------------------------------------------------------------------------
// Fused MLP: h2 = (relu(A@W1+b1))@W2 + b2 per 64-row tile; BN stats leave as
// per-block partials (no same-address global atomics).
// ---------------------------------------------------------------------------
__global__ __launch_bounds__(256) void mlp_fused(
    const unsigned short* __restrict__ A,    // M_PAD x 128 bf16
    const unsigned short* __restrict__ B1t,  // W1^T bf16 [n][k]
    const unsigned short* __restrict__ B2t,  // W2^T bf16 [n][k]
    const float* __restrict__ bias1, const float* __restrict__ bias2,
    unsigned short* __restrict__ outb,       // M_PAD x 128 bf16
    float* __restrict__ gpart) {             // GBLK x 256 partials
    __shared__ unsigned short As[M_TILE * LPITCH];   // 17408 B
    __shared__ unsigned short Bs[DIM * LPITCH];      // 34816 B
    int t = threadIdx.x;
    int row0 = blockIdx.x * M_TILE;
    int lane = t & 63, wv = t >> 6;
    int m = lane & 15, g = lane >> 4;

#pragma unroll
    for (int i = 0; i < 4; ++i) {
        int ch = t + 256 * i;
        int r = ch >> 4, cc = ch & 15;
        *(uint4*)(&As[r * LPITCH + cc * 8]) =
            *(const uint4*)(&A[(size_t)(row0 + r) * DIM + cc * 8]);
    }
#pragma unroll
    for (int i = 0; i < 8; ++i) {
        int ch = t + 256 * i;
        int n = ch >> 4, cc = ch & 15;
        *(uint4*)(&Bs[n * LPITCH + cc * 8]) =
            *(const uint4*)(&B1t[n * DIM + cc * 8]);
    }
    __syncthreads();

    floatx4 acc1[8] = {};
#pragma unroll
    for (int kc = 0; kc < 4; ++kc) {
        short8 a = *(const short8*)(&As[(wv * 16 + m) * LPITCH + kc * 32 + g * 8]);
#pragma unroll
        for (int tt = 0; tt < 8; ++tt) {
            short8 b = *(const short8*)(&Bs[(tt * 16 + m) * LPITCH + kc * 32 + g * 8]);
            acc1[tt] = __builtin_amdgcn_mfma_f32_16x16x32_bf16(a, b, acc1[tt], 0, 0, 0);
        }
    }
    __syncthreads();

    uint4 wbuf[8];
#pragma unroll
    for (int i = 0; i < 8; ++i) {
        int ch = t + 256 * i;
        int n = ch >> 4, cc = ch & 15;
        wbuf[i] = *(const uint4*)(&B2t[n * DIM + cc * 8]);
    }
#pragma unroll
    for (int tt = 0; tt < 8; ++tt) {
        int col = tt * 16 + m;
        float bv = bias1[col];
#pragma unroll
        for (int j = 0; j < 4; ++j) {
            int rl = wv * 16 + g * 4 + j;
            As[rl * LPITCH + col] = f2bf(fmaxf(acc1[tt][j] + bv, 0.f));
        }
    }
#pragma unroll
    for (int i = 0; i < 8; ++i) {
        int ch = t + 256 * i;
        int n = ch >> 4, cc = ch & 15;
        *(uint4*)(&Bs[n * LPITCH + cc * 8]) = wbuf[i];
    }
    __syncthreads();

    floatx4 acc2[8] = {};
#pragma unroll
    for (int kc = 0; kc < 4; ++kc) {
        short8 a = *(const short8*)(&As[(wv * 16 + m) * LPITCH + kc * 32 + g * 8]);
#pragma unroll
        for (int tt = 0; tt < 8; ++tt) {
            short8 b = *(const short8*)(&Bs[(tt * 16 + m) * LPITCH + kc * 32 + g * 8]);
            acc2[tt] = __builtin_amdgcn_mfma_f32_16x16x32_bf16(a, b, acc2[tt], 0, 0, 0);
        }
    }

    float* csum = (float*)As;
    float* csq = csum + DIM;
    __syncthreads();
    if (t < DIM) { csum[t] = 0.f; csq[t] = 0.f; }
    __syncthreads();
#pragma unroll
    for (int tt = 0; tt < 8; ++tt) {
        int col = tt * 16 + m;
        float bv = bias2[col];
        float s = 0.f, q = 0.f;
#pragma unroll
        for (int j = 0; j < 4; ++j) {
            int row = row0 + wv * 16 + g * 4 + j;
            float v = acc2[tt][j] + bv;
            outb[(size_t)row * DIM + col] = f2bf(v);
            if (row < N_NODES) { s += v; q += v * v; }
        }
        atomicAdd(&csum[col], s);
        atomicAdd(&csq[col], q);
    }
    __syncthreads();
    gpart[(size_t)blockIdx.x * 256 + t] = (t < DIM) ? csum[t] : csq[t - DIM];
}

// ---------------------------------------------------------------------------
// Reduce GBLK x 256 partials -> gstats[256].
// ---------------------------------------------------------------------------
__global__ __launch_bounds__(256) void reduce_stats(
    const float* __restrict__ gpart, float* __restrict__ gstats) {
    int t = threadIdx.x;
    int chunk = (GBLK + 31) / 32;            // 49
    int r0 = blockIdx.x * chunk;
    int r1 = r0 + chunk < GBLK ? r0 + chunk : GBLK;
    float s = 0.f;
    for (int r = r0; r < r1; ++r) s += gpart[(size_t)r * 256 + t];
    atomicAdd(&gstats[t], s);
}

// ---------------------------------------------------------------------------
// BN finalize (redundant per block) + apply.
// ---------------------------------------------------------------------------
__global__ __launch_bounds__(256) void bn_apply(
    const unsigned short* __restrict__ H2, const float* __restrict__ gstats,
    const float* __restrict__ gamma, const float* __restrict__ beta,
    float* __restrict__ out) {
    __shared__ float sc_s[DIM], sh_s[DIM];
    int t = threadIdx.x;
    if (t < DIM) {
        float mean = gstats[t] * (1.0f / N_NODES);
        float m2 = gstats[DIM + t] * (1.0f / N_NODES);
        float var = m2 - mean * mean;
        float inv = rsqrtf(var + EPS_BN);
        float sc = gamma[t] * inv;
        sc_s[t] = sc;
        sh_s[t] = beta[t] - mean * sc;
    }
    __syncthreads();
    int i = blockIdx.x * 256 + t;
    int j4 = (i & 31) * 4;
    ushort4 hv = ((const ushort4*)H2)[i];
    float4 o;
    o.x = bf2f(hv.x) * sc_s[j4 + 0] + sh_s[j4 + 0];
    o.y = bf2f(hv.y) * sc_s[j4 + 1] + sh_s[j4 + 1];
    o.z = bf2f(hv.z) * sc_s[j4 + 2] + sh_s[j4 + 2];
    o.w = bf2f(hv.w) * sc_s[j4 + 3] + sh_s[j4 + 3];
    ((float4*)out)[i] = o;
}

// ---------------------------------------------------------------------------
extern "C" void kernel_launch(void* const* d_in, const int* in_sizes, int n_in,
                              void* d_out, int out_size, void* d_ws,
                              size_t ws_size, hipStream_t stream) {
    (void)in_sizes; (void)n_in; (void)out_size; (void)ws_size;
    const float* x     = (const float*)d_in[0];
    const void*  eidx  = d_in[1];
    const float* W1    = (const float*)d_in[2];
    const float* b1    = (const float*)d_in[3];
    const float* W2    = (const float*)d_in[4];
    const float* b2    = (const float*)d_in[5];
    const float* gamma = (const float*)d_in[6];
    const float* beta  = (const float*)d_in[7];
    float* out = (float*)d_out;

    char* p = (char*)d_ws;
    auto alloc = [&](size_t bytes) {
        char* r = p;
        p += (bytes + 255) & ~(size_t)255;
        return r;
    };
    unsigned short* Hbf  = (unsigned short*)alloc((size_t)M_PAD * DIM * 2); // 25.6MB
    unsigned short* h2bf = (unsigned short*)alloc((size_t)M_PAD * DIM * 2); // 25.6MB
    // slots (8.4MB, packed 4B) alias h2bf: slots are dead before mlp writes h2
    unsigned* slots = (unsigned*)h2bf;
    unsigned short* xb = (unsigned short*)alloc((size_t)N_NODES * DIM * 2);  // 25.6MB
    float* gpart  = (float*)alloc((size_t)GBLK * 256 * 4);                   // 1.6MB
    int*   bcur   = (int*)alloc(NB * 4);
    unsigned short* W1t = (unsigned short*)alloc(DIM * DIM * 2);
    unsigned short* W2t = (unsigned short*)alloc(DIM * DIM * 2);
    float* gstats = (float*)alloc(2 * DIM * 4);

    xconv_w<<<N_NODES * DIM / 4 / 256, 256, 0, stream>>>(x, xb, W1, W2,
                                                         W1t, W2t, bcur, gstats);
    bin_scatter<<<NBLK, 256, 0, stream>>>(eidx, bcur, slots);
    agg_bucket<<<NB, 256, 0, stream>>>(xb, slots, bcur, Hbf);

    mlp_fused<<<GBLK, 256, 0, stream>>>(Hbf, W1t, W2t, b1, b2, h2bf, gpart);
    reduce_stats<<<32, 256, 0, stream>>>(gpart, gstats);
    bn_apply<<<(N_NODES * DIM / 4) / 256, 256, 0, stream>>>(h2bf, gstats,
                                                            gamma, beta, out);
}

// Round 3
// 309.220 us; speedup vs baseline: 4.2793x; 4.2793x over previous
//
#include <hip/hip_runtime.h>

#define N_NODES 100000
#define N_EDGES 1600000
#define DIM     128
#define EPS_BN  1e-5f
#define NB      512      // buckets
#define NPB     196      // nodes per bucket (512*196 >= 100000)
#define NBLK    256      // bin_scatter blocks
#define EPB     6250     // edges per bin_scatter block (256*6250 == N_EDGES)
#define CAP     4096     // slot capacity per bucket (mean 3125, sigma~56)
#define M_TILE  64
#define M_PAD   100032   // 1563 * 64
#define GBLK    1563     // M_PAD / M_TILE
#define PBLK    256      // persistent mlp blocks (1 per CU)
#define LPITCH  136      // LDS pitch in bf16 units (272B = 17*16B, b128-aligned)

typedef __attribute__((ext_vector_type(8))) short short8;
typedef __attribute__((ext_vector_type(4))) float floatx4;

__device__ __forceinline__ unsigned short f2bf(float f) {   // RNE bf16 bits
    unsigned u = __float_as_uint(f);
    return (unsigned short)((u + 0x7FFF + ((u >> 16) & 1)) >> 16);
}
__device__ __forceinline__ float bf2f(unsigned short b) {
    return __uint_as_float((unsigned)b << 16);
}

// int64 layout => odd int32 words all zero. Wave-uniform result.
__device__ __forceinline__ int detect64(const void* eidx) {
    int v = ((const int*)eidx)[2 * (threadIdx.x & 63) + 1];
    unsigned long long b = __ballot(v != 0);
    return (b == 0ULL) ? 1 : 0;
}
__device__ __forceinline__ int load_row(const void* eidx, int is64, int e) {
    if (is64) return (int)((const long long*)eidx)[e];
    return ((const int*)eidx)[e];
}
__device__ __forceinline__ int load_col(const void* eidx, int is64, int e) {
    if (is64) return (int)((const long long*)eidx)[N_EDGES + e];
    return ((const int*)eidx)[N_EDGES + e];
}

// ---------------------------------------------------------------------------
// convert_w + workspace init: blocks 0/1 transpose W1/W2 to bf16 [n][k];
// block 2 zeroes bcur + gstats.
// ---------------------------------------------------------------------------
__global__ void convert_w(const float* __restrict__ W1,
                          const float* __restrict__ W2,
                          unsigned short* __restrict__ W1t,
                          unsigned short* __restrict__ W2t,
                          int* __restrict__ bcur, float* __restrict__ gstats) {
    if (blockIdx.x == 2) {
        int t = threadIdx.x;
        bcur[t] = 0;
        bcur[256 + t] = 0;
        if (t < 2 * DIM) gstats[t] = 0.f;
        return;
    }
    const float* W = blockIdx.x ? W2 : W1;
    unsigned short* Wt = blockIdx.x ? W2t : W1t;
    for (int i = threadIdx.x; i < DIM * DIM; i += 256) {
        int k = i >> 7, n = i & 127;
        Wt[n * DIM + k] = f2bf(W[i]);
    }
}

// ---------------------------------------------------------------------------
// bin_scatter_x: hist -> LDS scan -> per-bucket global range claim -> LDS
// bucket-sorted staging (packed 4B: row_local<<24 | col) with precomputed
// absolute slot addresses -> LINEAR copy out. Then each block grid-strides a
// chunk of the x f32->bf16 conversion (independent streaming, overlaps other
// blocks' LDS/atomic phases). LDS: 3*2KB tables + 25KB stage + 25KB gaddr.
// ---------------------------------------------------------------------------
__global__ __launch_bounds__(256) void bin_scatter_x(
    const void* eidx, int* bcur, unsigned* __restrict__ slots,
    const float* __restrict__ x, unsigned short* __restrict__ xb) {
    __shared__ int lh[NB];
    __shared__ int lbase[NB];
    __shared__ int loff[NB];
    __shared__ unsigned stage[EPB];
    __shared__ int gaddr[EPB];
    int t = threadIdx.x;
    int is64 = detect64(eidx);
    lh[t] = 0; lh[t + 256] = 0;
    __syncthreads();
    int base = blockIdx.x * EPB;
    for (int i = t; i < EPB; i += 256) {
        int r = load_row(eidx, is64, base + i);
        atomicAdd(&lh[r / NPB], 1);
    }
    __syncthreads();
    // inclusive scan of lh[0..511] into loff (256 threads, 2 elems each)
    loff[t] = lh[t]; loff[t + 256] = lh[t + 256];
    __syncthreads();
    for (int off = 1; off < NB; off <<= 1) {
        int a0 = (t >= off) ? loff[t - off] : 0;
        int a1 = (t + 256 >= off) ? loff[t + 256 - off] : 0;
        __syncthreads();
        loff[t] += a0; loff[t + 256] += a1;
        __syncthreads();
    }
    // claim global ranges, make loff exclusive, reset lh for scatter cursors
#pragma unroll
    for (int q = 0; q < 2; ++q) {
        int i = t + 256 * q;
        int c = lh[i];
        lbase[i] = c ? atomicAdd(&bcur[i], c) : 0;
        loff[i] -= c;
        lh[i] = 0;
    }
    __syncthreads();
    for (int i = t; i < EPB; i += 256) {
        int r = load_row(eidx, is64, base + i);
        int c = load_col(eidx, is64, base + i);
        int b = r / NPB;
        int pos = atomicAdd(&lh[b], 1);
        int idx = loff[b] + pos;
        stage[idx] = ((unsigned)(r - b * NPB) << 24) | (unsigned)c;
        gaddr[idx] = b * CAP + lbase[b] + pos;
    }
    __syncthreads();
    for (int i = t; i < EPB; i += 256)        // linear: runs coalesce to lines
        slots[gaddr[i]] = stage[i];
    // ---- fused xconv: grid-stride f32 -> bf16 (no barrier needed) ----
    for (int i = blockIdx.x * 256 + t; i < N_NODES * DIM / 4; i += NBLK * 256) {
        float4 v = ((const float4*)x)[i];
        ushort4 o;
        o.x = f2bf(v.x); o.y = f2bf(v.y); o.z = f2bf(v.z); o.w = f2bf(v.w);
        ((ushort4*)xb)[i] = o;
    }
}

// ---------------------------------------------------------------------------
// build_csr: in-block redundant scan of bucket counts, then LDS
// hist/scan/scatter of this bucket's packed pairs, coalesced out.
// ---------------------------------------------------------------------------
__global__ __launch_bounds__(256) void build_csr(const unsigned* __restrict__ slots,
                                                 const int* __restrict__ bcnt,
                                                 int* __restrict__ rowst,
                                                 int* __restrict__ cols) {
    __shared__ int tmp[NB];
    __shared__ int hist[256];
    __shared__ int excl[256];
    __shared__ int cur[256];
    __shared__ int colbuf[CAP];
    int t = threadIdx.x;
    int b = blockIdx.x;
    // inclusive scan of bcnt into tmp
    tmp[t] = bcnt[t]; tmp[t + 256] = bcnt[t + 256];
    __syncthreads();
    for (int off = 1; off < NB; off <<= 1) {
        int a0 = (t >= off) ? tmp[t - off] : 0;
        int a1 = (t + 256 >= off) ? tmp[t + 256 - off] : 0;
        __syncthreads();
        tmp[t] += a0; tmp[t + 256] += a1;
        __syncthreads();
    }
    int cnt = bcnt[b];
    int s = tmp[b] - cnt;                     // exclusive start
    int node0 = b * NPB;
    int nn = N_NODES - node0;
    if (nn > NPB) nn = NPB;
    const unsigned* pairs = slots + (size_t)b * CAP;
    hist[t] = 0;
    if (b == NB - 1 && t == 0) rowst[N_NODES] = N_EDGES;
    __syncthreads();
    for (int i = t; i < cnt; i += 256)
        atomicAdd(&hist[(int)(pairs[i] >> 24)], 1);
    __syncthreads();
    int v = hist[t];
    excl[t] = v;
    __syncthreads();
    for (int off = 1; off < 256; off <<= 1) {
        int a = (t >= off) ? excl[t - off] : 0;
        __syncthreads();
        excl[t] += a;
        __syncthreads();
    }
    int ex = excl[t] - v;
    if (t < nn) rowst[node0 + t] = s + ex;
    cur[t] = ex;
    __syncthreads();
    for (int i = t; i < cnt; i += 256) {
        unsigned pr = pairs[i];
        int pos = atomicAdd(&cur[pr >> 24], 1);
        colbuf[pos] = (int)(pr & 0xFFFFFFu);
    }
    __syncthreads();
    for (int i = t; i < cnt; i += 256) cols[s + i] = colbuf[i];
}

// ---------------------------------------------------------------------------
// Aggregation + residual: Hbf[n] = bf16(xb[n] + sum xb[c]).  (round-0 proven:
// 59.7us, 3.74 TB/s.)  One wave per node; fully-predicated 16/32-deep load
// groups put the whole neighbor list in flight in one round trip.
// ---------------------------------------------------------------------------
__global__ __launch_bounds__(256) void agg_kernel(
    const unsigned short* __restrict__ xb,
    const int* __restrict__ row_start, const int* __restrict__ cols,
    unsigned short* __restrict__ Hbf) {
    int wave = threadIdx.x >> 6;
    int lane = threadIdx.x & 63;
    int node = blockIdx.x * 4 + wave;
    const unsigned* xbw = (const unsigned*)xb;     // 64 words per row
    unsigned selfw = xbw[(size_t)node * 64 + lane];
    float2 acc;
    acc.x = __uint_as_float(selfw << 16);
    acc.y = __uint_as_float(selfw & 0xffff0000u);
    int s = row_start[node], e = row_start[node + 1];
    s = __builtin_amdgcn_readfirstlane(s);
    e = __builtin_amdgcn_readfirstlane(e);
    int d = e - s;
    if (d <= 16) {
        unsigned pw[16];
#pragma unroll
        for (int u = 0; u < 16; ++u) {
            int idx = s + u;
            int ci = (idx < e) ? idx : s;              // clamp: dup row, L1 hit
            pw[u] = xbw[(size_t)cols[ci] * 64 + lane];
        }
#pragma unroll
        for (int u = 0; u < 16; ++u) {
            unsigned w = (u < d) ? pw[u] : 0u;         // masked accumulate
            acc.x += __uint_as_float(w << 16);
            acc.y += __uint_as_float(w & 0xffff0000u);
        }
    } else if (d <= 32) {
        unsigned pw[32];
#pragma unroll
        for (int u = 0; u < 32; ++u) {
            int idx = s + u;
            int ci = (idx < e) ? idx : s;
            pw[u] = xbw[(size_t)cols[ci] * 64 + lane];
        }
#pragma unroll
        for (int u = 0; u < 32; ++u) {
            unsigned w = (u < d) ? pw[u] : 0u;
            acc.x += __uint_as_float(w << 16);
            acc.y += __uint_as_float(w & 0xffff0000u);
        }
    } else {
        int j = s;
        for (; j + 16 <= e; j += 16) {
            unsigned pw[16];
#pragma unroll
            for (int u = 0; u < 16; ++u)
                pw[u] = xbw[(size_t)cols[j + u] * 64 + lane];
#pragma unroll
            for (int u = 0; u < 16; ++u) {
                acc.x += __uint_as_float(pw[u] << 16);
                acc.y += __uint_as_float(pw[u] & 0xffff0000u);
            }
        }
        for (; j < e; ++j) {
            unsigned pv = xbw[(size_t)cols[j] * 64 + lane];
            acc.x += __uint_as_float(pv << 16);
            acc.y += __uint_as_float(pv & 0xffff0000u);
        }
    }
    unsigned pack = (unsigned)f2bf(acc.x) | ((unsigned)f2bf(acc.y) << 16);
    ((unsigned*)Hbf)[(size_t)node * 64 + lane] = pack;
}

// ---------------------------------------------------------------------------
// Persistent fused MLP: 256 blocks (1/CU). W1,W2 staged in LDS ONCE; A-tiles
// double-buffered with register prefetch overlapping the MFMAs; 2 barriers
// per tile; BN partials accumulate in registers across tiles, one LDS reduce
// per block at the end. LDS = 2*17408 (As dbuf) + 2*34816 (Bs1,Bs2) = 104448B.
// ---------------------------------------------------------------------------
__global__ __launch_bounds__(256) void mlp_persist(
    const unsigned short* __restrict__ A,    // M_PAD x 128 bf16
    const unsigned short* __restrict__ B1t,  // W1^T bf16 [n][k]
    const unsigned short* __restrict__ B2t,  // W2^T bf16 [n][k]
    const float* __restrict__ bias1, const float* __restrict__ bias2,
    unsigned short* __restrict__ outb,       // M_PAD x 128 bf16
    float* __restrict__ gpart) {             // PBLK x 256 partials
    __shared__ unsigned short As[2][M_TILE * LPITCH];
    __shared__ unsigned short Bs1[DIM * LPITCH];
    __shared__ unsigned short Bs2[DIM * LPITCH];
    int t = threadIdx.x;
    int lane = t & 63, wv = t >> 6;
    int m = lane & 15, g = lane >> 4;
    int r_ = t >> 4, c_ = t & 15;            // A-stage slot: rows r_+16i, chunk c_

    // prologue: W1,W2 -> LDS; A(tile blockIdx) -> As[0]
#pragma unroll
    for (int i = 0; i < 8; ++i) {
        int ch = t + 256 * i;
        int n = ch >> 4, cc = ch & 15;
        *(uint4*)(&Bs1[n * LPITCH + cc * 8]) = *(const uint4*)(&B1t[n * DIM + cc * 8]);
        *(uint4*)(&Bs2[n * LPITCH + cc * 8]) = *(const uint4*)(&B2t[n * DIM + cc * 8]);
    }
    int tl = blockIdx.x;
    {
        int row0 = tl * M_TILE;
#pragma unroll
        for (int i = 0; i < 4; ++i)
            *(uint4*)(&As[0][(r_ + 16 * i) * LPITCH + c_ * 8]) =
                *(const uint4*)(&A[(size_t)(row0 + r_ + 16 * i) * DIM + c_ * 8]);
    }
    float bv1[8], bv2[8];
#pragma unroll
    for (int tt = 0; tt < 8; ++tt) {
        bv1[tt] = bias1[tt * 16 + m];
        bv2[tt] = bias2[tt * 16 + m];
    }
    float bsum[8] = {}, bsq[8] = {};
    __syncthreads();

    int cur = 0;
    while (tl < GBLK) {
        int nxt = tl + PBLK;
        bool pf = (nxt < GBLK);               // block-uniform
        uint4 ald[4];
        if (pf) {
            int row0n = nxt * M_TILE;
#pragma unroll
            for (int i = 0; i < 4; ++i)
                ald[i] = *(const uint4*)(&A[(size_t)(row0n + r_ + 16 * i) * DIM + c_ * 8]);
        }
        // GEMM1: relu input from As[cur]
        floatx4 acc1[8] = {};
#pragma unroll
        for (int kc = 0; kc < 4; ++kc) {
            short8 a = *(const short8*)(&As[cur][(wv * 16 + m) * LPITCH + kc * 32 + g * 8]);
#pragma unroll
            for (int tt = 0; tt < 8; ++tt) {
                short8 b = *(const short8*)(&Bs1[(tt * 16 + m) * LPITCH + kc * 32 + g * 8]);
                acc1[tt] = __builtin_amdgcn_mfma_f32_16x16x32_bf16(a, b, acc1[tt], 0, 0, 0);
            }
        }
        __syncthreads();                      // all waves done reading As[cur]
        // relu -> As[cur]; prefetched A(t+1) -> As[cur^1]
#pragma unroll
        for (int tt = 0; tt < 8; ++tt) {
            int col = tt * 16 + m;
#pragma unroll
            for (int j = 0; j < 4; ++j) {
                int rl = wv * 16 + g * 4 + j;
                As[cur][rl * LPITCH + col] = f2bf(fmaxf(acc1[tt][j] + bv1[tt], 0.f));
            }
        }
        if (pf) {
#pragma unroll
            for (int i = 0; i < 4; ++i)
                *(uint4*)(&As[cur ^ 1][(r_ + 16 * i) * LPITCH + c_ * 8]) = ald[i];
        }
        __syncthreads();
        // GEMM2
        floatx4 acc2[8] = {};
#pragma unroll
        for (int kc = 0; kc < 4; ++kc) {
            short8 a = *(const short8*)(&As[cur][(wv * 16 + m) * LPITCH + kc * 32 + g * 8]);
#pragma unroll
            for (int tt = 0; tt < 8; ++tt) {
                short8 b = *(const short8*)(&Bs2[(tt * 16 + m) * LPITCH + kc * 32 + g * 8]);
                acc2[tt] = __builtin_amdgcn_mfma_f32_16x16x32_bf16(a, b, acc2[tt], 0, 0, 0);
            }
        }
        int row0 = tl * M_TILE;
#pragma unroll
        for (int tt = 0; tt < 8; ++tt) {
            int col = tt * 16 + m;
#pragma unroll
            for (int j = 0; j < 4; ++j) {
                int row = row0 + wv * 16 + g * 4 + j;
                float v = acc2[tt][j] + bv2[tt];
                outb[(size_t)row * DIM + col] = f2bf(v);
                if (row < N_NODES) { bsum[tt] += v; bsq[tt] += v * v; }
            }
        }
        tl = nxt; cur ^= 1;
        // no barrier needed: next GEMM1 reads As[cur^1] (protected by the
        // barrier after it); next tile's As writes happen after that barrier,
        // which is after this tile's GEMM2 reads in every wave's program order.
    }

    // final BN partial reduce (reuse As as scratch)
    float* csum = (float*)As;
    float* csq = csum + DIM;
    __syncthreads();
    if (t < DIM) { csum[t] = 0.f; csq[t] = 0.f; }
    __syncthreads();
#pragma unroll
    for (int tt = 0; tt < 8; ++tt) {
        atomicAdd(&csum[tt * 16 + m], bsum[tt]);
        atomicAdd(&csq[tt * 16 + m], bsq[tt]);
    }
    __syncthreads();
    gpart[(size_t)blockIdx.x * 256 + t] = (t < DIM) ? csum[t] : csq[t - DIM];
}

// ---------------------------------------------------------------------------
// Reduce PBLK x 256 partials -> gstats[256].
// ---------------------------------------------------------------------------
__global__ __launch_bounds__(256) void reduce_stats(
    const float* __restrict__ gpart, float* __restrict__ gstats) {
    int t = threadIdx.x;
    int r0 = blockIdx.x * (PBLK / 32);
    float s = 0.f;
    for (int r = r0; r < r0 + PBLK / 32; ++r) s += gpart[(size_t)r * 256 + t];
    atomicAdd(&gstats[t], s);
}

// ---------------------------------------------------------------------------
// BN finalize (redundant per block) + apply.
// ---------------------------------------------------------------------------
__global__ __launch_bounds__(256) void bn_apply(
    const unsigned short* __restrict__ H2, const float* __restrict__ gstats,
    const float* __restrict__ gamma, const float* __restrict__ beta,
    float* __restrict__ out) {
    __shared__ float sc_s[DIM], sh_s[DIM];
    int t = threadIdx.x;
    if (t < DIM) {
        float mean = gstats[t] * (1.0f / N_NODES);
        float m2 = gstats[DIM + t] * (1.0f / N_NODES);
        float var = m2 - mean * mean;
        float inv = rsqrtf(var + EPS_BN);
        float sc = gamma[t] * inv;
        sc_s[t] = sc;
        sh_s[t] = beta[t] - mean * sc;
    }
    __syncthreads();
    int i = blockIdx.x * 256 + t;
    int j4 = (i & 31) * 4;
    ushort4 hv = ((const ushort4*)H2)[i];
    float4 o;
    o.x = bf2f(hv.x) * sc_s[j4 + 0] + sh_s[j4 + 0];
    o.y = bf2f(hv.y) * sc_s[j4 + 1] + sh_s[j4 + 1];
    o.z = bf2f(hv.z) * sc_s[j4 + 2] + sh_s[j4 + 2];
    o.w = bf2f(hv.w) * sc_s[j4 + 3] + sh_s[j4 + 3];
    ((float4*)out)[i] = o;
}

// ---------------------------------------------------------------------------
extern "C" void kernel_launch(void* const* d_in, const int* in_sizes, int n_in,
                              void* d_out, int out_size, void* d_ws,
                              size_t ws_size, hipStream_t stream) {
    (void)in_sizes; (void)n_in; (void)out_size; (void)ws_size;
    const float* x     = (const float*)d_in[0];
    const void*  eidx  = d_in[1];
    const float* W1    = (const float*)d_in[2];
    const float* b1    = (const float*)d_in[3];
    const float* W2    = (const float*)d_in[4];
    const float* b2    = (const float*)d_in[5];
    const float* gamma = (const float*)d_in[6];
    const float* beta  = (const float*)d_in[7];
    float* out = (float*)d_out;

    char* p = (char*)d_ws;
    auto alloc = [&](size_t bytes) {
        char* r = p;
        p += (bytes + 255) & ~(size_t)255;
        return r;
    };
    unsigned short* Hbf  = (unsigned short*)alloc((size_t)M_PAD * DIM * 2); // 25.6MB
    unsigned short* h2bf = (unsigned short*)alloc((size_t)M_PAD * DIM * 2); // 25.6MB
    // slots (8.4MB, packed 4B) alias h2bf: dead before mlp writes h2
    unsigned* slots = (unsigned*)h2bf;
    unsigned short* xb = (unsigned short*)alloc((size_t)N_NODES * DIM * 2);  // 25.6MB
    int*   cols   = (int*)alloc((size_t)(N_EDGES + 64) * 4);                 // 6.4MB
    float* gpart  = (float*)alloc((size_t)PBLK * 256 * 4);                   // 256KB
    int*   rowst  = (int*)alloc((size_t)(N_NODES + 1) * 4);
    int*   bcur   = (int*)alloc(NB * 4);
    unsigned short* W1t = (unsigned short*)alloc(DIM * DIM * 2);
    unsigned short* W2t = (unsigned short*)alloc(DIM * DIM * 2);
    float* gstats = (float*)alloc(2 * DIM * 4);

    convert_w<<<3, 256, 0, stream>>>(W1, W2, W1t, W2t, bcur, gstats);
    bin_scatter_x<<<NBLK, 256, 0, stream>>>(eidx, bcur, slots, x, xb);
    build_csr<<<NB, 256, 0, stream>>>(slots, bcur, rowst, cols);

    agg_kernel<<<N_NODES / 4, 256, 0, stream>>>(xb, rowst, cols, Hbf);

    mlp_persist<<<PBLK, 256, 0, stream>>>(Hbf, W1t, W2t, b1, b2, h2bf, gpart);
    reduce_stats<<<32, 256, 0, stream>>>(gpart, gstats);
    bn_apply<<<(N_NODES * DIM / 4) / 256, 256, 0, stream>>>(h2bf, gstats,
                                                            gamma, beta, out);
}